// Round 7
// baseline (293.947 us; speedup 1.0000x reference)
//
#include <hip/hip_runtime.h>
#include <stdint.h>

#define DECAY 0.99f
#define OMDECAY 0.01f
#define EPSV 1e-5f

// Problem: z (32,256,32,32) fp32; tokens N=32768, D=256, K=1024 codes.
// out (floats): zq[0,8388608) idx[8388608,8421376) loss[8421376]
//               new_embed[8421377,..) new_cs[8683521,..) new_ea[8684545,..)
//   best64 scratch overlays new_embed region at out+8421378 (65536 dwords),
//   dead before finalize_embed overwrites it.
// ws (dwords):
//   B_hi32   0        (131072)   1024x256 f16 packed 2/dword   } es (262144 fp32)
//   B_lo32   131072   (131072)                                 } reused after vq_mfma
//   A_hi32   262144   (4194304)  32768x256 f16, token-major
//   A_lo32   4456448  (4194304)
//   perm     8650752  (32768)    int, tokens sorted by code
//   offsets  8683520  (1024)     int, segment starts
//   cursor   8684544  (1024)     int, atomic cursors
//   cs       8912896  (1024)     fp32 histogram
//   loss     8913920  (1024, 1 used)
//   enorm    8914944  (1024)
//   csnorm   8915968  (1024)

typedef _Float16 half8 __attribute__((ext_vector_type(8)));
typedef float floatx4 __attribute__((ext_vector_type(4)));

typedef __attribute__((address_space(1))) const uint32_t gu32;
typedef __attribute__((address_space(3))) uint32_t lu32;

__device__ __forceinline__ void gld16(uint32_t* l, const uint32_t* g) {
    __builtin_amdgcn_global_load_lds((gu32*)g, (lu32*)l, 16, 0, 0);
}

__device__ __forceinline__ uint32_t pack_hl(float v) {
    _Float16 h = (_Float16)v;
    _Float16 lo = (_Float16)(v - (float)h);
    return (uint32_t)__builtin_bit_cast(unsigned short, h) |
           ((uint32_t)__builtin_bit_cast(unsigned short, lo) << 16);
}

// monotone float -> uint32 (ascending order preserved)
__device__ __forceinline__ unsigned int encf(float s) {
    unsigned int b = __builtin_bit_cast(unsigned int, s);
    return (b & 0x80000000u) ? ~b : (b | 0x80000000u);
}

// ---- prep: split embed + enorm + zero cs/loss + init best64 keys ----
__global__ void prep_embed(const float* __restrict__ embed,
                           unsigned short* __restrict__ B_hi16,
                           unsigned short* __restrict__ B_lo16,
                           float* __restrict__ enorm,
                           float* __restrict__ cs /* + loss contiguous */,
                           uint32_t* __restrict__ b64i) {
    __shared__ float ws4[4];
    const int k = blockIdx.x;
    const int tid = threadIdx.x;
    const int lane = tid & 63;
    const int wv = tid >> 6;
    int idx = k * 256 + tid;
    float v = embed[idx];
    _Float16 h = (_Float16)v;
    _Float16 lo = (_Float16)(v - (float)h);
    B_hi16[idx] = __builtin_bit_cast(unsigned short, h);
    B_lo16[idx] = __builtin_bit_cast(unsigned short, lo);
    float s = v * v;
    for (int off = 32; off > 0; off >>= 1) s += __shfl_down(s, off);
    if (lane == 0) ws4[wv] = s;
    __syncthreads();
    if (tid == 0) enorm[k] = ws4[0] + ws4[1] + ws4[2] + ws4[3];
    if (k < 256) b64i[k * 256 + tid] = 0xFFFFFFFFu;   // best64 = +inf keys
    if (k == 0) {
        for (int i = tid; i < 2048; i += 256) cs[i] = 0.f;   // cs + loss_sum
    }
}

// ---- prep: z (b,d,h,w) -> token-major f16 hi/lo A[t][d] ----
__global__ void split_z(const float* __restrict__ z,
                        uint32_t* __restrict__ A_hi32,
                        uint32_t* __restrict__ A_lo32) {
    __shared__ uint32_t sp[32 * 258];
    const int lane = threadIdx.x & 63;
    const int wv   = threadIdx.x >> 6;
    const int t0   = blockIdx.x * 32;
    const int b    = t0 >> 10;
    const int hw0  = t0 & 1023;
    const int l32  = lane & 31;
    const int dh   = lane >> 5;

    for (int dp = wv; dp < 128; dp += 4) {
        int dd = dp * 2 + dh;
        float v = z[b * 262144 + dd * 1024 + hw0 + l32];
        sp[l32 * 258 + dd] = pack_hl(v);
    }
    __syncthreads();
    for (int r = wv; r < 32; r += 4) {
#pragma unroll
        for (int h2 = 0; h2 < 2; ++h2) {
            int dpair = h2 * 64 + lane;
            uint32_t u0 = sp[r * 258 + 2 * dpair];
            uint32_t u1 = sp[r * 258 + 2 * dpair + 1];
            A_hi32[(t0 + r) * 128 + dpair] = (u0 & 0xffffu) | (u1 << 16);
            A_lo32[(t0 + r) * 128 + dpair] = (u0 >> 16) | (u1 & 0xffff0000u);
        }
    }
}

// ---- main: MFMA distance GEMM + argmin via packed atomicMin ----
// 512 blocks = 256 token-groups(128 tok) x 2 code-halves (512 codes).
// A fragments: global->VGPR (token-major rows, L2-resident).
// B tiles: LDS double-buffered; next tile prefetched before compute.
__global__ __launch_bounds__(256, 2) void vq_mfma(
    const uint32_t* __restrict__ A_hi32,
    const uint32_t* __restrict__ A_lo32,
    const uint32_t* __restrict__ B_hi32,
    const uint32_t* __restrict__ B_lo32,
    const float* __restrict__ enorm,
    unsigned long long* __restrict__ best64)
{
    __shared__ __align__(16) _Float16 BsH[2][256 * 32];   // 2 x 16 KB
    __shared__ __align__(16) _Float16 BsL[2][256 * 32];   // 2 x 16 KB

    const int lane = threadIdx.x & 63;
    const int w    = threadIdx.x >> 6;
    const int q    = lane >> 4;
    const int c16  = lane & 15;
    const int t0   = (blockIdx.x >> 1) * 128;   // token base
    const int cb   = (blockIdx.x & 1) * 512;    // code-half base
    const int lane4 = lane >> 2;
    const int dd8   = (lane & 3) * 8;

    // per-lane A row base (dwords): row = t0 + i*16 + c16, frag at + dc*16 + q*4
    const uint32_t* aH0 = A_hi32 + (t0 + c16) * 128 + q * 4;
    const uint32_t* aL0 = A_lo32 + (t0 + c16) * 128 + q * 4;

    // ---- stage helper: stage step's B tile into buf[step&1] ----
    auto stageB = [&](int step) {
        const int nc_s = step >> 3;
        const int dc_s = step & 7;
        const int d0h  = (dc_s * 32 + dd8) >> 1;   // dword offset in code row
        _Float16* dH = BsH[step & 1];
        _Float16* dL = BsL[step & 1];
        for (int s = w; s < 32; s += 4) {
            int ss = s & 15;
            int code = cb + nc_s * 256 + ss * 16 + lane4;
            if (s < 16) {
                gld16((uint32_t*)dH + ss * 256, B_hi32 + code * 128 + d0h);
            } else {
                gld16((uint32_t*)dL + ss * 256, B_lo32 + code * 128 + d0h);
            }
        }
    };

    stageB(0);
    __syncthreads();

    for (int nc = 0; nc < 2; ++nc) {
        floatx4 acc[8][4];
#pragma unroll
        for (int i = 0; i < 8; ++i)
#pragma unroll
            for (int j = 0; j < 4; ++j)
                acc[i][j] = (floatx4){0.f, 0.f, 0.f, 0.f};

        for (int dc = 0; dc < 8; ++dc) {
            const int step = nc * 8 + dc;
            // prefetch next B tile into the other buffer (flies during compute)
            if (step + 1 < 16) stageB(step + 1);

            const _Float16* bsh = BsH[step & 1];
            const _Float16* bsl = BsL[step & 1];
            half8 bH[4], bL[4];
#pragma unroll
            for (int j = 0; j < 4; ++j) {
                int off = (w * 64 + j * 16 + c16) * 32 + q * 8;
                bH[j] = *(const half8*)(bsh + off);
                bL[j] = *(const half8*)(bsl + off);
            }
#pragma unroll
            for (int i = 0; i < 8; ++i) {
                half8 aH = *(const half8*)(aH0 + i * 2048 + dc * 16);
                half8 aL = *(const half8*)(aL0 + i * 2048 + dc * 16);
#pragma unroll
                for (int j = 0; j < 4; ++j) {
                    acc[i][j] = __builtin_amdgcn_mfma_f32_16x16x32_f16(aH, bH[j], acc[i][j], 0, 0, 0);
                    acc[i][j] = __builtin_amdgcn_mfma_f32_16x16x32_f16(aH, bL[j], acc[i][j], 0, 0, 0);
                    acc[i][j] = __builtin_amdgcn_mfma_f32_16x16x32_f16(aL, bH[j], acc[i][j], 0, 0, 0);
                }
            }
            __syncthreads();   // prefetch done + frag reads done before reuse
        }

        // score = ||e||^2 - 2*dot ; per-nc best, tie -> lowest code
        float bestv[32];
        int   besti[32];
#pragma unroll
        for (int s = 0; s < 32; ++s) { bestv[s] = 3.4e38f; besti[s] = 0; }
#pragma unroll
        for (int j = 0; j < 4; ++j) {
            int code = cb + nc * 256 + w * 64 + j * 16 + c16;
            float en = enorm[code];
#pragma unroll
            for (int i = 0; i < 8; ++i)
#pragma unroll
                for (int r = 0; r < 4; ++r) {
                    float sc = en - 2.0f * acc[i][j][r];
                    int slot = i * 4 + r;
                    if (sc < bestv[slot] || (sc == bestv[slot] && code < besti[slot])) {
                        bestv[slot] = sc; besti[slot] = code;
                    }
                }
        }
        // butterfly argmin across the 16 c16-lanes sharing each token
#pragma unroll
        for (int slot = 0; slot < 32; ++slot) {
            float v = bestv[slot]; int bi = besti[slot];
#pragma unroll
            for (int m = 1; m < 16; m <<= 1) {
                float ov = __shfl_xor(v, m);
                int   oi = __shfl_xor(bi, m);
                if (ov < v || (ov == v && oi < bi)) { v = ov; bi = oi; }
            }
            bestv[slot] = v; besti[slot] = bi;
        }
        // distributed packed atomicMin: lane c16 owns slots c16, c16+16
#pragma unroll
        for (int slot = 0; slot < 32; ++slot) {
            if (c16 == (slot & 15)) {
                int tok = (slot >> 2) * 16 + q * 4 + (slot & 3);
                unsigned long long key =
                    ((unsigned long long)encf(bestv[slot]) << 32) |
                    (unsigned int)besti[slot];
                atomicMin(&best64[t0 + tok], key);
            }
        }
    }
}

// ---- merge: decode best64 -> idx/cs, write zq + loss ----
__global__ __launch_bounds__(256) void merge_zq(
    const unsigned long long* __restrict__ best64,
    const float* __restrict__ z,
    const float* __restrict__ embed,
    float* __restrict__ out_zq,
    float* __restrict__ out_idx,
    float* __restrict__ cs,
    float* __restrict__ loss_sum)
{
    __shared__ int sidx[128];
    const int tid = threadIdx.x;
    const int lane = tid & 63;
    const int w = tid >> 6;
    const int t0 = blockIdx.x * 128;

    if (tid < 128) {
        int bi = (int)(unsigned int)(best64[t0 + tid] & 0xffffffffULL);
        sidx[tid] = bi;
        out_idx[t0 + tid] = (float)bi;
        atomicAdd(&cs[bi], 1.0f);
    }
    __syncthreads();

    const int b_idx = t0 >> 10;
    const int hw0   = t0 & 1023;
    const int zbase = b_idx * 262144 + hw0;
    const int ka = sidx[lane];
    const int kb = sidx[lane + 64];
    float lsum = 0.f;
    for (int d = w; d < 256; d += 4) {
        float zv0 = z[zbase + d * 1024 + lane];
        float zv1 = z[zbase + d * 1024 + lane + 64];
        float e0 = embed[ka * 256 + d];
        float e1 = embed[kb * 256 + d];
        out_zq[zbase + d * 1024 + lane]      = zv0 + (e0 - zv0);
        out_zq[zbase + d * 1024 + lane + 64] = zv1 + (e1 - zv1);
        float d0f = zv0 - e0, d1f = zv1 - e1;
        lsum += d0f * d0f + d1f * d1f;
    }
    for (int off = 32; off > 0; off >>= 1) lsum += __shfl_down(lsum, off);
    if (lane == 0) atomicAdd(loss_sum, lsum);
}

// ---- finalize: loss, new_cluster, csnorm, prefix-scan (wave shuffles) ----
__global__ void vq_finalize_small(const float* __restrict__ cluster_size,
                                  const float* __restrict__ cs,
                                  const float* __restrict__ loss_sum,
                                  float* __restrict__ out_loss,
                                  float* __restrict__ out_ncs,
                                  float* __restrict__ csnorm,
                                  int* __restrict__ offsets,
                                  int* __restrict__ cursor)
{
    __shared__ float wsum[16];
    __shared__ float wncs[16];
    __shared__ float stot[1];
    const int k = threadIdx.x;
    const int lane = k & 63;
    const int wv = k >> 6;
    float cnt = cs[k];
    float ncs = cluster_size[k] * DECAY + OMDECAY * cnt;
    out_ncs[k] = ncs;
    float sc = cnt;
#pragma unroll
    for (int d = 1; d < 64; d <<= 1) {
        float up = __shfl_up(sc, d);
        if (lane >= d) sc += up;
    }
    if (lane == 63) wsum[wv] = sc;
    float ns = ncs;
    for (int off = 32; off > 0; off >>= 1) ns += __shfl_down(ns, off);
    if (lane == 0) wncs[wv] = ns;
    __syncthreads();
    if (wv == 0) {
        float v = (lane < 16) ? wsum[lane] : 0.f;
#pragma unroll
        for (int d = 1; d < 16; d <<= 1) {
            float up = __shfl_up(v, d);
            if (lane >= d) v += up;
        }
        if (lane < 16) wsum[lane] = v;
    } else if (wv == 1) {
        float t = (lane < 16) ? wncs[lane] : 0.f;
        for (int off = 32; off > 0; off >>= 1) t += __shfl_down(t, off);
        if (lane == 0) stot[0] = t;
    }
    __syncthreads();
    float incl = sc + (wv ? wsum[wv - 1] : 0.f);
    int excl = __float2int_rn(incl - cnt);
    offsets[k] = excl;
    cursor[k]  = excl;
    float n = stot[0];
    csnorm[k] = (ncs + EPSV) / (n + 1024.0f * EPSV) * n;
    if (k == 0) out_loss[0] = loss_sum[0] / 8388608.0f;
}

// ---- counting-sort scatter + es zeroing ----
__global__ void scatter_perm(const float* __restrict__ out_idx,
                             int* __restrict__ cursor,
                             int* __restrict__ perm,
                             float* __restrict__ es)
{
    int t = blockIdx.x * 256 + threadIdx.x;
#pragma unroll
    for (int i = 0; i < 8; ++i) es[t + i * 32768] = 0.f;
    int code = (int)out_idx[t];
    int pos = atomicAdd(&cursor[code], 1);
    perm[pos] = t;
}

// ---- chunked segmented sum over the SORTED token list ----
__global__ void es_sum(const uint32_t* __restrict__ A_hi32,
                       const uint32_t* __restrict__ A_lo32,
                       const int* __restrict__ perm,
                       const float* __restrict__ out_idx,
                       float* __restrict__ es)
{
    __shared__ int sperm[32];
    __shared__ int scode[32];
    const int base = blockIdx.x * 32;
    const int tid = threadIdx.x;
    const int j = tid & 127;
    const uint32_t* __restrict__ A = (tid >> 7) ? A_lo32 : A_hi32;
    if (tid < 32) {
        int t = perm[base + tid];
        sperm[tid] = t;
        scode[tid] = (int)out_idx[t];
    }
    __syncthreads();

    float s0 = 0.f, s1 = 0.f;
    int cur = scode[0];
    uint32_t pu[2];
    pu[0] = A[sperm[0] * 128 + j];
    pu[1] = A[sperm[1] * 128 + j];
#pragma unroll
    for (int i = 0; i < 32; ++i) {
        uint32_t u = pu[i & 1];
        if (i + 2 < 32) pu[i & 1] = A[sperm[i + 2] * 128 + j];
        int code = scode[i];
        if (code != cur) {
            atomicAdd(&es[cur * 256 + 2 * j],     s0);
            atomicAdd(&es[cur * 256 + 2 * j + 1], s1);
            s0 = 0.f; s1 = 0.f; cur = code;
        }
        s0 += (float)__builtin_bit_cast(_Float16, (unsigned short)(u & 0xffffu));
        s1 += (float)__builtin_bit_cast(_Float16, (unsigned short)(u >> 16));
    }
    atomicAdd(&es[cur * 256 + 2 * j],     s0);
    atomicAdd(&es[cur * 256 + 2 * j + 1], s1);
}

// ---- EMA finalize for embed_avg / embed (overwrites best64 scratch) ----
__global__ void finalize_embed(const float* __restrict__ embed_avg,
                               const float* __restrict__ es,
                               const float* __restrict__ csnorm,
                               float* __restrict__ out_embed,
                               float* __restrict__ out_nea)
{
    int idx = blockIdx.x * 256 + threadIdx.x;
    int k = idx >> 8;
    float nea = embed_avg[idx] * DECAY + OMDECAY * es[idx];
    out_nea[idx] = nea;
    out_embed[idx] = nea / csnorm[k];
}

extern "C" void kernel_launch(void* const* d_in, const int* in_sizes, int n_in,
                              void* d_out, int out_size, void* d_ws, size_t ws_size,
                              hipStream_t stream) {
    const float* z            = (const float*)d_in[0];
    const float* embed        = (const float*)d_in[1];
    const float* cluster_size = (const float*)d_in[2];
    const float* embed_avg    = (const float*)d_in[3];
    float* out = (float*)d_out;
    uint32_t* ws32 = (uint32_t*)d_ws;

    uint32_t* B_hi32 = ws32 + 0;
    uint32_t* B_lo32 = ws32 + 131072;
    uint32_t* A_hi32 = ws32 + 262144;
    uint32_t* A_lo32 = ws32 + 4456448;
    int* perm        = (int*)(ws32 + 8650752);
    int* offsets     = (int*)(ws32 + 8683520);
    int* cursor      = (int*)(ws32 + 8684544);
    float* cs        = (float*)(ws32 + 8912896);
    float* loss_sum  = (float*)(ws32 + 8913920);
    float* enorm     = (float*)(ws32 + 8914944);
    float* csnorm    = (float*)(ws32 + 8915968);
    float* es        = (float*)(ws32 + 0);        // reuses B_hi/B_lo after vq_mfma
    // best64 scratch overlays the new_embed output region (8-byte aligned)
    unsigned long long* best64 = (unsigned long long*)(out + 8421378);

    prep_embed<<<1024, 256, 0, stream>>>(embed, (unsigned short*)B_hi32,
                                         (unsigned short*)B_lo32, enorm, cs,
                                         (uint32_t*)best64);
    split_z<<<1024, 256, 0, stream>>>(z, A_hi32, A_lo32);
    vq_mfma<<<512, 256, 0, stream>>>(A_hi32, A_lo32, B_hi32, B_lo32, enorm, best64);
    merge_zq<<<256, 256, 0, stream>>>(best64, z, embed,
                                      out, out + 8388608, cs, loss_sum);
    vq_finalize_small<<<1, 1024, 0, stream>>>(cluster_size, cs, loss_sum,
                                              out + 8421376, out + 8683521, csnorm,
                                              offsets, cursor);
    scatter_perm<<<128, 256, 0, stream>>>(out + 8388608, cursor, perm, es);
    es_sum<<<1024, 256, 0, stream>>>(A_hi32, A_lo32, perm, out + 8388608, es);
    finalize_embed<<<1024, 256, 0, stream>>>(embed_avg, es, csnorm,
                                             out + 8421377, out + 8684545);
}